// Round 9
// baseline (101.392 us; speedup 1.0000x reference)
//
#include <hip/hip_runtime.h>
#include <stdint.h>

#define NB 64
#define NN 1024
#define CDIM 512
#define KK 64
#define XPAD 536   // x_sm row stride in ush: 1072 B = 67*16 (b128-aligned), 268 words ≡ 12 mod 32

typedef __attribute__((ext_vector_type(4))) float f32x4;
typedef __attribute__((ext_vector_type(8))) short short8;
typedef __attribute__((ext_vector_type(4))) unsigned short u16x4;

__device__ __forceinline__ unsigned short f2bf(float f) {
  unsigned int u = __float_as_uint(f);
  return (unsigned short)((u + 0x7fffu + ((u >> 16) & 1u)) >> 16);
}
__device__ __forceinline__ float bf2f(unsigned short h) {
  return __uint_as_float(((unsigned int)h) << 16);
}

__device__ __forceinline__ void lgkm_barrier() {
  // raw workgroup barrier that does NOT drain vmcnt (k2 only)
  asm volatile("s_waitcnt lgkmcnt(0)" ::: "memory");
  __builtin_amdgcn_sched_barrier(0);
  __builtin_amdgcn_s_barrier();
}

// ---------------- K0: centers fp32 -> bf16 ----------------
__global__ __launch_bounds__(256) void k0_cvt(const float* __restrict__ cc,
                                              unsigned short* __restrict__ ccb) {
  int i = blockIdx.x * 256 + threadIdx.x;   // grid sized exactly KK*CDIM/256
  ccb[i] = f2bf(cc[i]);
}

// ---- K1: LINEAR-access logits + softmax + a^T emit + xT emit ----
// grid: (16 n-chunks, 64 b) = 1024 blocks, 256 thr = 4 waves, 2 blocks/CU.
// All global traffic is request-minimal:
//   x loads: 32 f32x4/thread, lane-contiguous 1KB/instr (8x128B req)
//   xT stores: u32 lanes-contiguous, 8x128B req/instr
//   a_t stores: u32 lanes-contiguous (as before)
// Frag formation from LDS (x_sm [64][XPAD] bf16); xT pack from LDS u32-pair reads.
__global__ __launch_bounds__(256, 2) void k1_assign(const float* __restrict__ x,
    const unsigned short* __restrict__ ccb, unsigned short* __restrict__ a_t,
    unsigned int* __restrict__ xT32) {
  const int b = blockIdx.y;
  const int n0 = blockIdx.x << 6;
  const int tid = threadIdx.x;
  const int w = tid >> 6;
  const int l = tid & 63;
  const int lr = l & 15;
  const int lg = l >> 4;

  __shared__ unsigned short x_sm[64 * XPAD];  // 68608 B, [n][c] bf16 padded
  __shared__ unsigned short a_sm[KK * 64];    // 8192 B, [kc][r] byte-swizzled

  // ---- stage: x[b][n0..n0+64)[0..512) fp32 -> bf16 LDS, fully linear loads ----
  {
    const float* xb = x + (((size_t)(b * NN + n0)) << 9);
    #pragma unroll 4
    for (int i = 0; i < 32; ++i) {
      const int f4 = (i << 8) + tid;          // f32x4 index in [0, 8192)
      const int n = f4 >> 7;                  // 128 f32x4 per row
      const int c4 = (f4 & 127) << 2;
      f32x4 v = *(const f32x4*)(xb + ((size_t)n << 9) + c4);
      u16x4 pk;
      pk[0] = f2bf(v[0]); pk[1] = f2bf(v[1]);
      pk[2] = f2bf(v[2]); pk[3] = f2bf(v[3]);
      *(u16x4*)&x_sm[n * XPAD + c4] = pk;
    }
  }
  __syncthreads();

  // ---- MFMA logits: wave w owns n-rows [16w, 16w+16) ----
  const unsigned short* cb = ccb + lr * CDIM + (lg << 3);
  f32x4 acc0 = {0.f, 0.f, 0.f, 0.f}, acc1 = acc0, acc2 = acc0, acc3 = acc0;
  #pragma unroll 4
  for (int cs = 0; cs < CDIM; cs += 32) {
    short8 af = *(const short8*)&x_sm[((w << 4) + lr) * XPAD + cs + (lg << 3)];
    short8 b0 = *(const short8*)(cb + cs);
    short8 b1 = *(const short8*)(cb + 16 * CDIM + cs);
    short8 b2 = *(const short8*)(cb + 32 * CDIM + cs);
    short8 b3 = *(const short8*)(cb + 48 * CDIM + cs);
    acc0 = __builtin_amdgcn_mfma_f32_16x16x32_bf16(af, b0, acc0, 0, 0, 0);
    acc1 = __builtin_amdgcn_mfma_f32_16x16x32_bf16(af, b1, acc1, 0, 0, 0);
    acc2 = __builtin_amdgcn_mfma_f32_16x16x32_bf16(af, b2, acc2, 0, 0, 0);
    acc3 = __builtin_amdgcn_mfma_f32_16x16x32_bf16(af, b3, acc3, 0, 0, 0);
  }

  // ---- softmax (D: lane holds logits[row=(l>>4)*4+j][kc=t*16+(l&15)]) ----
  const int swzb = (lr & 7) << 3;
  #pragma unroll
  for (int j = 0; j < 4; ++j) {
    float m = fmaxf(fmaxf(acc0[j], acc1[j]), fmaxf(acc2[j], acc3[j]));
    m = fmaxf(m, __shfl_xor(m, 1));
    m = fmaxf(m, __shfl_xor(m, 2));
    m = fmaxf(m, __shfl_xor(m, 4));
    m = fmaxf(m, __shfl_xor(m, 8));
    float e0 = __expf(acc0[j] - m);
    float e1 = __expf(acc1[j] - m);
    float e2 = __expf(acc2[j] - m);
    float e3 = __expf(acc3[j] - m);
    float s = e0 + e1 + e2 + e3;
    s += __shfl_xor(s, 1); s += __shfl_xor(s, 2);
    s += __shfl_xor(s, 4); s += __shfl_xor(s, 8);
    float inv = 1.0f / s;
    e0 *= inv; e1 *= inv; e2 *= inv; e3 *= inv;
    int r = (w << 4) + (lg << 2) + j;
    int rs = r ^ swzb;
    a_sm[( lr       << 6) + rs] = f2bf(e0);
    a_sm[((16 + lr) << 6) + rs] = f2bf(e1);
    a_sm[((32 + lr) << 6) + rs] = f2bf(e2);
    a_sm[((48 + lr) << 6) + rs] = f2bf(e3);
  }
  __syncthreads();

  // ---- a_t drain: a_t[b][kc][n0..], u32 (2 bf16), lanes-contiguous ----
  {
    const unsigned int* au = (const unsigned int*)a_sm;
    #pragma unroll
    for (int e0 = 0; e0 < 2048; e0 += 256) {
      int e = e0 + tid;
      int kc = e >> 5, n2 = e & 31;
      unsigned int v = au[(kc << 5) + (n2 ^ ((kc & 7) << 2))];
      *((unsigned int*)(a_t + (((size_t)((b << 6) + kc)) << 10) + n0) + n2) = v;
    }
  }

  // ---- xT drain: xT[b][c][n-pair] u32; LDS u32-pair reads + pack ----
  // iter: 256 thr = 32 nq x 8 c-pairs; stores are 32-lane-contiguous u32,
  // 8x128B requests per instr.
  {
    const int nq = tid & 31;           // n-pair within chunk
    const int cp0 = tid >> 5;          // c-pair slot 0..7
    const size_t gb = (((size_t)b) << 18) + (n0 >> 1) + nq;  // b*512*512
    #pragma unroll 4
    for (int i = 0; i < 32; ++i) {
      const int c0 = ((i << 3) + cp0) << 1;   // even c
      unsigned int lo = *(const unsigned int*)&x_sm[(nq << 1) * XPAD + c0];
      unsigned int hi = *(const unsigned int*)&x_sm[((nq << 1) + 1) * XPAD + c0];
      unsigned int v0 = (lo & 0xffffu) | (hi << 16);           // column c0
      unsigned int v1 = (lo >> 16) | (hi & 0xffff0000u);       // column c0+1
      xT32[gb + (((size_t)c0) << 9)] = v0;
      xT32[gb + (((size_t)(c0 + 1)) << 9)] = v1;
    }
  }
}

// ---- K2: agg = a^T x via MFMA; a_sum computed in-kernel from A-frags ----
// grid: (8 c-slices, 64 b) = 512 blocks, 256 thr = 4 waves (k-split 16 each).
// Per 64-n chunk: stage xT tile [64c][64n] via 8 coalesced u32 loads/thread into
// stride-38 LDS (dbuf); A-frags direct from a_t; 8 MFMA/iter/wave. T14 prefetch;
// raw lgkm-only barriers keep prefetched global loads in flight across sync.
#define XRS 38
__global__ __launch_bounds__(256) void k2_agg(
    const unsigned short* __restrict__ a_t, const unsigned int* __restrict__ xT32,
    const float* __restrict__ cc, float* __restrict__ out,
    float* __restrict__ sumsq) {
  const int b = blockIdx.y;
  const int c0 = blockIdx.x << 6;
  const int tid = threadIdx.x;
  const int w = tid >> 6;
  const int l = tid & 63;
  const int lr = l & 15;
  const int lg = l >> 4;

  __shared__ unsigned int xs[2][64 * XRS];  // 9728 B each
  __shared__ float red[4];

  f32x4 acc[4];
  #pragma unroll
  for (int i = 0; i < 4; ++i) acc[i] = (f32x4){0.f, 0.f, 0.f, 0.f};
  float ssum = 0.f;   // per-lane partial of a_sum[k=16w+lr]

  const unsigned short* ap =
      a_t + (((size_t)((b << 6) + (w << 4) + lr)) << 10) + (lg << 3);
  const unsigned int* xg =
      xT32 + (((size_t)((b << 9) + c0 + (tid >> 5))) << 9) + (tid & 31);

  #pragma unroll
  for (int p = 0; p < 8; ++p) {
    const int f = (p << 8) + tid;
    xs[0][(f >> 5) * XRS + (f & 31)] = xg[(((size_t)p) << 12)]; // p*8 rows *512
  }
  short8 a_cur0 = *(const short8*)(ap);
  short8 a_cur1 = *(const short8*)(ap + 32);
  lgkm_barrier();

  for (int it = 0; it < 16; ++it) {
    const int cur = it & 1;
    unsigned int xr[8];
    short8 a_nxt0, a_nxt1;
    if (it < 15) {
      const int nu = (it + 1) << 5;
      #pragma unroll
      for (int p = 0; p < 8; ++p) xr[p] = xg[(((size_t)p) << 12) + nu];
      a_nxt0 = *(const short8*)(ap + ((it + 1) << 6));
      a_nxt1 = *(const short8*)(ap + ((it + 1) << 6) + 32);
    }
    #pragma unroll
    for (int i = 0; i < 8; ++i)
      ssum += bf2f((unsigned short)a_cur0[i]) + bf2f((unsigned short)a_cur1[i]);
    #pragma unroll
    for (int ns = 0; ns < 64; ns += 32) {
      const short8 af = ns == 0 ? a_cur0 : a_cur1;
      #pragma unroll
      for (int ct = 0; ct < 4; ++ct) {
        const int row = (ct << 4) + lr;
        const unsigned long long* bp = (const unsigned long long*)
            &xs[cur][row * XRS + (ns >> 1) + (lg << 2)];
        union { unsigned long long q[2]; short8 s; } u;
        u.q[0] = bp[0];
        u.q[1] = bp[1];
        acc[ct] = __builtin_amdgcn_mfma_f32_16x16x32_bf16(af, u.s, acc[ct], 0, 0, 0);
      }
    }
    if (it < 15) {
      #pragma unroll
      for (int p = 0; p < 8; ++p) {
        const int f = (p << 8) + tid;
        xs[cur ^ 1][(f >> 5) * XRS + (f & 31)] = xr[p];
      }
      a_cur0 = a_nxt0;
      a_cur1 = a_nxt1;
    }
    lgkm_barrier();
  }

  // a_sum reduce over lg groups; lane lr holds a_sum for k=16w+lr
  ssum += __shfl_xor(ssum, 16);
  ssum += __shfl_xor(ssum, 32);

  float lsum = 0.f;
  #pragma unroll
  for (int j = 0; j < 4; ++j) {
    const float asum_e = __shfl(ssum, (lg << 2) + j);   // a_sum[k=16w+lg*4+j]
    #pragma unroll
    for (int ct = 0; ct < 4; ++ct) {
      int k = (w << 4) + (lg << 2) + j;
      int c = c0 + (ct << 4) + lr;
      float v = acc[ct][j] - asum_e * cc[k * CDIM + c];
      out[((size_t)b << 15) + (k << 9) + c] = v;
      lsum += v * v;
    }
  }
  lsum += __shfl_xor(lsum, 1);  lsum += __shfl_xor(lsum, 2);
  lsum += __shfl_xor(lsum, 4);  lsum += __shfl_xor(lsum, 8);
  lsum += __shfl_xor(lsum, 16); lsum += __shfl_xor(lsum, 32);
  if (l == 0) red[w] = lsum;
  __syncthreads();
  if (tid == 0) atomicAdd(&sumsq[b], red[0] + red[1] + red[2] + red[3]);
}

// ---------------- K3: l2 normalize per batch ----------------
__global__ __launch_bounds__(256) void k3_norm(float* __restrict__ out,
                                               const float* __restrict__ sumsq) {
  int idx = blockIdx.x * 256 + threadIdx.x;   // grid exact: 2048*256 = 2M/4
  int b = idx >> 13;                          // 8192 float4 per batch
  float s = sumsq[b];
  float scale = 1.0f / sqrtf(fmaxf(s, 1e-12f));
  f32x4* io = (f32x4*)out;
  f32x4 v = io[idx];
  v[0] *= scale; v[1] *= scale; v[2] *= scale; v[3] *= scale;
  io[idx] = v;
}

extern "C" void kernel_launch(void* const* d_in, const int* in_sizes, int n_in,
                              void* d_out, int out_size, void* d_ws, size_t ws_size,
                              hipStream_t stream) {
  const float* x  = (const float*)d_in[0];
  const float* cc = (const float*)d_in[1];
  float* out = (float*)d_out;
  char* ws = (char*)d_ws;
  // ws: [a_t bf16 8MiB][ccb 64KiB][sumsq 256B] ... [xT 64MiB @16MiB]
  unsigned short* a_t = (unsigned short*)ws;
  unsigned short* ccb = (unsigned short*)(ws + (8u << 20));
  float* sumsq = (float*)(ws + (8u << 20) + (64u << 10));
  unsigned int* xT32 = (unsigned int*)(ws + (16u << 20));

  (void)hipMemsetAsync(sumsq, 0, NB * 4, stream);
  k0_cvt<<<dim3((KK * CDIM) / 256), 256, 0, stream>>>(cc, ccb);
  k1_assign<<<dim3(16, NB), 256, 0, stream>>>(x, ccb, a_t, xT32);
  k2_agg<<<dim3(8, NB), 256, 0, stream>>>(a_t, xT32, cc, out, sumsq);
  k3_norm<<<dim3(2048), 256, 0, stream>>>(out, sumsq);
}

// Round 10
// 79.034 us; speedup vs baseline: 1.2829x; 1.2829x over previous
//
#include <hip/hip_runtime.h>
#include <stdint.h>

#define NB 64
#define NN 1024
#define CDIM 512
#define KK 64

typedef __attribute__((ext_vector_type(4))) float f32x4;
typedef __attribute__((ext_vector_type(8))) short short8;

__device__ __forceinline__ unsigned short f2bf(float f) {
  unsigned int u = __float_as_uint(f);
  return (unsigned short)((u + 0x7fffu + ((u >> 16) & 1u)) >> 16);
}
__device__ __forceinline__ float bf2f(unsigned short h) {
  return __uint_as_float(((unsigned int)h) << 16);
}

__device__ __forceinline__ void lgkm_barrier() {
  // raw workgroup barrier that does NOT drain vmcnt (k2 only)
  asm volatile("s_waitcnt lgkmcnt(0)" ::: "memory");
  __builtin_amdgcn_sched_barrier(0);
  __builtin_amdgcn_s_barrier();
}

// ---------------- K0: centers fp32 -> bf16 ----------------
__global__ __launch_bounds__(256) void k0_cvt(const float* __restrict__ cc,
                                              unsigned short* __restrict__ ccb) {
  int i = blockIdx.x * 256 + threadIdx.x;   // grid sized exactly KK*CDIM/256
  ccb[i] = f2bf(cc[i]);
}

// ---- K1: logits MFMA + softmax + a^T emit + xT emit — wave-private, chunked ----
// grid: (4, 64 b), 256 thr = 4 independent waves; wave owns n-chunk nc = bx*4+w
// (64 n-rows). Emitted layouts are CHUNK-CONTIGUOUS so every wave's global
// stores are one linear stream (DRAM-page friendly):
//   xT[b][nc][c=512][n2=32 u32]  (64 KB/wave)
//   a_t[b][nc][k=64][n2=32 u32]  ( 8 KB/wave)
__global__ __launch_bounds__(256, 1) void k1_assign(const float* __restrict__ x,
    const unsigned short* __restrict__ ccb, unsigned int* __restrict__ a_t32,
    unsigned int* __restrict__ xT32) {
  const int b = blockIdx.y;
  const int tid = threadIdx.x;
  const int w = tid >> 6;
  const int l = tid & 63;
  const int lr = l & 15;
  const int lg = l >> 4;
  const int nc = (blockIdx.x << 2) + w;
  const int n0 = nc << 6;
  const int codd = l & 1;

  __shared__ unsigned int xsw_all[4][32 * 33];   // 4.2 KB per wave, private
  __shared__ unsigned int asw_all[4][64 * 33];   // 8.4 KB per wave, private
  unsigned int* xsw = xsw_all[w];
  unsigned int* asw = asw_all[w];

  const float* xr = x + ((size_t)b * NN + n0 + lr) * CDIM + (lg << 3);
  const unsigned short* cb = ccb + lr * CDIM + (lg << 3);
  const size_t xTbase = ((size_t)((b << 4) + nc)) << 14;  // *512*32 u32
  const size_t atbase = ((size_t)((b << 4) + nc)) << 11;  // *64*32 u32

  f32x4 acc[4][4];
  #pragma unroll
  for (int i = 0; i < 4; ++i)
    #pragma unroll
    for (int j = 0; j < 4; ++j) acc[i][j] = (f32x4){0.f, 0.f, 0.f, 0.f};

  #pragma unroll 2
  for (int step = 0; step < 16; ++step) {
    const int cs = step << 5;
    short8 af[4];
    #pragma unroll
    for (int tn = 0; tn < 4; ++tn) {
      f32x4 xa = *(const f32x4*)(xr + (size_t)(tn << 4) * CDIM + cs);
      f32x4 xb = *(const f32x4*)(xr + (size_t)(tn << 4) * CDIM + cs + 4);
      short8 t;
      t[0] = (short)f2bf(xa[0]); t[1] = (short)f2bf(xa[1]);
      t[2] = (short)f2bf(xa[2]); t[3] = (short)f2bf(xa[3]);
      t[4] = (short)f2bf(xb[0]); t[5] = (short)f2bf(xb[1]);
      t[6] = (short)f2bf(xb[2]); t[7] = (short)f2bf(xb[3]);
      af[tn] = t;
    }
    short8 bq0 = *(const short8*)(cb + cs);
    short8 bq1 = *(const short8*)(cb + 16 * CDIM + cs);
    short8 bq2 = *(const short8*)(cb + 32 * CDIM + cs);
    short8 bq3 = *(const short8*)(cb + 48 * CDIM + cs);
    #pragma unroll
    for (int tn = 0; tn < 4; ++tn) {
      acc[tn][0] = __builtin_amdgcn_mfma_f32_16x16x32_bf16(af[tn], bq0, acc[tn][0], 0, 0, 0);
      acc[tn][1] = __builtin_amdgcn_mfma_f32_16x16x32_bf16(af[tn], bq1, acc[tn][1], 0, 0, 0);
      acc[tn][2] = __builtin_amdgcn_mfma_f32_16x16x32_bf16(af[tn], bq2, acc[tn][2], 0, 0, 0);
      acc[tn][3] = __builtin_amdgcn_mfma_f32_16x16x32_bf16(af[tn], bq3, acc[tn][3], 0, 0, 0);
    }
    // transpose af -> private slab: lane-pair (n, n^1) via shfl_xor(1).
    #pragma unroll
    for (int tn = 0; tn < 4; ++tn) {
      #pragma unroll
      for (int q = 0; q < 4; ++q) {
        unsigned int own = ((const unsigned int*)&af[tn])[q];
        unsigned int oth = (unsigned int)__shfl_xor((int)own, 1);
        unsigned int v = codd ? ((oth >> 16) | (own & 0xffff0000u))
                              : ((own & 0xffffu) | (oth << 16));
        xsw[((lg << 3) + (q << 1) + codd) * 33 + (tn << 3) + (lr >> 1)] = v;
      }
    }
    // wave-synchronous drain: CONTIGUOUS 256 B per instr (2 c-rows x 128 B)
    #pragma unroll
    for (int i = 0; i < 16; ++i) {
      const int row = (i << 1) + (l >> 5);
      xT32[xTbase + ((size_t)(cs + row) << 5) + (l & 31)] = xsw[row * 33 + (l & 31)];
    }
  }

  // in-register softmax over k (4 tk accs x 16 lr lanes), in place
  #pragma unroll
  for (int tn = 0; tn < 4; ++tn) {
    #pragma unroll
    for (int j = 0; j < 4; ++j) {
      float m = fmaxf(fmaxf(acc[tn][0][j], acc[tn][1][j]),
                      fmaxf(acc[tn][2][j], acc[tn][3][j]));
      m = fmaxf(m, __shfl_xor(m, 1));
      m = fmaxf(m, __shfl_xor(m, 2));
      m = fmaxf(m, __shfl_xor(m, 4));
      m = fmaxf(m, __shfl_xor(m, 8));
      float e0 = __expf(acc[tn][0][j] - m);
      float e1 = __expf(acc[tn][1][j] - m);
      float e2 = __expf(acc[tn][2][j] - m);
      float e3 = __expf(acc[tn][3][j] - m);
      float s = e0 + e1 + e2 + e3;
      s += __shfl_xor(s, 1); s += __shfl_xor(s, 2);
      s += __shfl_xor(s, 4); s += __shfl_xor(s, 8);
      float inv = 1.0f / s;
      acc[tn][0][j] = e0 * inv;
      acc[tn][1][j] = e1 * inv;
      acc[tn][2][j] = e2 * inv;
      acc[tn][3][j] = e3 * inv;
    }
  }
  // a^T pack: n-pair (j=2jp, 2jp+1) lives in the SAME lane -> no shuffle
  #pragma unroll
  for (int tn = 0; tn < 4; ++tn)
    #pragma unroll
    for (int tk = 0; tk < 4; ++tk)
      #pragma unroll
      for (int jp = 0; jp < 2; ++jp) {
        unsigned int v = (unsigned int)f2bf(acc[tn][tk][2 * jp]) |
                         ((unsigned int)f2bf(acc[tn][tk][2 * jp + 1]) << 16);
        asw[((tk << 4) + lr) * 33 + (tn << 3) + (lg << 1) + jp] = v;
      }
  // drain a-slab: CONTIGUOUS 256 B per instr (2 k-rows x 128 B)
  #pragma unroll
  for (int i = 0; i < 32; ++i) {
    const int k = (i << 1) + (l >> 5);
    a_t32[atbase + ((size_t)k << 5) + (l & 31)] = asw[k * 33 + (l & 31)];
  }
}

// ---- K2: agg = a^T x via MFMA; chunked inputs; a_sum computed in-kernel ----
// grid: (8 c-slices, 64 b) = 512 blocks, 256 thr = 4 waves (k-split 16 each).
// Per chunk it: stage xT[b][it][c0..c0+64)][64n] (8 KB CONTIGUOUS) via 8 u32
// loads/thread into stride-38 LDS (dbuf); A-frags direct from a_t[b][it][k][n].
// T14 prefetch; raw lgkm-only barriers keep prefetched loads in flight.
#define XRS 38
__global__ __launch_bounds__(256) void k2_agg(
    const unsigned short* __restrict__ a_t, const unsigned int* __restrict__ xT32,
    const float* __restrict__ cc, float* __restrict__ out,
    float* __restrict__ sumsq) {
  const int b = blockIdx.y;
  const int c0 = blockIdx.x << 6;
  const int tid = threadIdx.x;
  const int w = tid >> 6;
  const int l = tid & 63;
  const int lr = l & 15;
  const int lg = l >> 4;

  __shared__ unsigned int xs[2][64 * XRS];  // 9728 B each
  __shared__ float red[4];

  f32x4 acc[4];
  #pragma unroll
  for (int i = 0; i < 4; ++i) acc[i] = (f32x4){0.f, 0.f, 0.f, 0.f};
  float ssum = 0.f;   // per-lane partial of a_sum[k=16w+lr]

  // A-frag pointer: chunk-stride 4096 ush; row k=16w+lr (64 ush), off lg*8
  const unsigned short* ap =
      a_t + (((size_t)(b << 4)) << 12) + (((w << 4) + lr) << 6) + (lg << 3);
  // xT stage pointer: chunk-stride 16384 u32; c-row c0 + tid>>5, col tid&31
  const unsigned int* xg =
      xT32 + (((size_t)(b << 4)) << 14) + ((c0 + (tid >> 5)) << 5) + (tid & 31);

  // ---- prologue: stage chunk 0, load chunk-0 A-frags ----
  #pragma unroll
  for (int p = 0; p < 8; ++p) {
    const int f = (p << 8) + tid;
    xs[0][(f >> 5) * XRS + (f & 31)] = xg[p << 8];
  }
  short8 a_cur0 = *(const short8*)(ap);
  short8 a_cur1 = *(const short8*)(ap + 32);
  lgkm_barrier();

  for (int it = 0; it < 16; ++it) {
    const int cur = it & 1;
    unsigned int xr[8];
    short8 a_nxt0, a_nxt1;
    if (it < 15) {
      const size_t cho = ((size_t)(it + 1)) << 14;      // u32 chunk offset
      const size_t cha = ((size_t)(it + 1)) << 12;      // ush chunk offset
      #pragma unroll
      for (int p = 0; p < 8; ++p) xr[p] = xg[cho + (p << 8)];
      a_nxt0 = *(const short8*)(ap + cha);
      a_nxt1 = *(const short8*)(ap + cha + 32);
    }
    #pragma unroll
    for (int i = 0; i < 8; ++i)
      ssum += bf2f((unsigned short)a_cur0[i]) + bf2f((unsigned short)a_cur1[i]);
    #pragma unroll
    for (int ns = 0; ns < 64; ns += 32) {
      const short8 af = ns == 0 ? a_cur0 : a_cur1;
      #pragma unroll
      for (int ct = 0; ct < 4; ++ct) {
        const int row = (ct << 4) + lr;
        const unsigned long long* bp = (const unsigned long long*)
            &xs[cur][row * XRS + (ns >> 1) + (lg << 2)];
        union { unsigned long long q[2]; short8 s; } u;
        u.q[0] = bp[0];
        u.q[1] = bp[1];
        acc[ct] = __builtin_amdgcn_mfma_f32_16x16x32_bf16(af, u.s, acc[ct], 0, 0, 0);
      }
    }
    if (it < 15) {
      #pragma unroll
      for (int p = 0; p < 8; ++p) {
        const int f = (p << 8) + tid;
        xs[cur ^ 1][(f >> 5) * XRS + (f & 31)] = xr[p];
      }
      a_cur0 = a_nxt0;
      a_cur1 = a_nxt1;
    }
    lgkm_barrier();
  }

  // a_sum reduce over lg groups; lane lr holds a_sum for k=16w+lr
  ssum += __shfl_xor(ssum, 16);
  ssum += __shfl_xor(ssum, 32);

  float lsum = 0.f;
  #pragma unroll
  for (int j = 0; j < 4; ++j) {
    const float asum_e = __shfl(ssum, (lg << 2) + j);   // a_sum[k=16w+lg*4+j]
    #pragma unroll
    for (int ct = 0; ct < 4; ++ct) {
      int k = (w << 4) + (lg << 2) + j;
      int c = c0 + (ct << 4) + lr;
      float v = acc[ct][j] - asum_e * cc[k * CDIM + c];
      out[((size_t)b << 15) + (k << 9) + c] = v;
      lsum += v * v;
    }
  }
  lsum += __shfl_xor(lsum, 1);  lsum += __shfl_xor(lsum, 2);
  lsum += __shfl_xor(lsum, 4);  lsum += __shfl_xor(lsum, 8);
  lsum += __shfl_xor(lsum, 16); lsum += __shfl_xor(lsum, 32);
  if (l == 0) red[w] = lsum;
  __syncthreads();
  if (tid == 0) atomicAdd(&sumsq[b], red[0] + red[1] + red[2] + red[3]);
}

// ---------------- K3: l2 normalize per batch ----------------
__global__ __launch_bounds__(256) void k3_norm(float* __restrict__ out,
                                               const float* __restrict__ sumsq) {
  int idx = blockIdx.x * 256 + threadIdx.x;   // grid exact: 2048*256 = 2M/4
  int b = idx >> 13;                          // 8192 float4 per batch
  float s = sumsq[b];
  float scale = 1.0f / sqrtf(fmaxf(s, 1e-12f));
  f32x4* io = (f32x4*)out;
  f32x4 v = io[idx];
  v[0] *= scale; v[1] *= scale; v[2] *= scale; v[3] *= scale;
  io[idx] = v;
}

extern "C" void kernel_launch(void* const* d_in, const int* in_sizes, int n_in,
                              void* d_out, int out_size, void* d_ws, size_t ws_size,
                              hipStream_t stream) {
  const float* x  = (const float*)d_in[0];
  const float* cc = (const float*)d_in[1];
  float* out = (float*)d_out;
  char* ws = (char*)d_ws;
  // ws: [a_t bf16 8MiB][ccb 64KiB][sumsq 256B] ... [xT 64MiB @16MiB]
  unsigned short* a_t = (unsigned short*)ws;
  unsigned int* a_t32 = (unsigned int*)ws;
  unsigned short* ccb = (unsigned short*)(ws + (8u << 20));
  float* sumsq = (float*)(ws + (8u << 20) + (64u << 10));
  unsigned int* xT32 = (unsigned int*)(ws + (16u << 20));

  (void)hipMemsetAsync(sumsq, 0, NB * 4, stream);
  k0_cvt<<<dim3((KK * CDIM) / 256), 256, 0, stream>>>(cc, ccb);
  k1_assign<<<dim3(4, NB), 256, 0, stream>>>(x, ccb, a_t32, xT32);
  k2_agg<<<dim3(8, NB), 256, 0, stream>>>(a_t, xT32, cc, out, sumsq);
  k3_norm<<<dim3(2048), 256, 0, stream>>>(out, sumsq);
}